// Round 5
// baseline (552.165 us; speedup 1.0000x reference)
//
#include <hip/hip_runtime.h>
#include <hip/hip_bf16.h>
#include <math.h>

#define N 4096
#define D 128
#define EPSV 1e-8f

typedef __attribute__((ext_vector_type(8))) short bf16x8;
typedef __attribute__((ext_vector_type(4))) float f32x4;

__device__ __forceinline__ float lrelu(float x){ return x > 0.f ? x : 0.2f*x; }

__device__ __forceinline__ ushort bf16_hi(float x){
  __hip_bfloat16 h = __float2bfloat16(x);
  return *reinterpret_cast<ushort*>(&h);
}
__device__ __forceinline__ float bf16_tof(ushort u){
  __hip_bfloat16 h = *reinterpret_cast<__hip_bfloat16*>(&u);
  return __bfloat162float(h);
}

__device__ __forceinline__ float wave_sum(float v){
  #pragma unroll
  for (int off = 32; off; off >>= 1) v += __shfl_down(v, off);
  return v;
}
__device__ __forceinline__ float block_sum256(float v, float* red){
  v = wave_sum(v);
  if ((threadIdx.x & 63) == 0) red[threadIdx.x >> 6] = v;
  __syncthreads();
  float r = (red[0] + red[1]) + (red[2] + red[3]);
  __syncthreads();
  return r;
}

// dis[i] = 1/sqrt(sum_j adj[i][j] + 1e-8)
__global__ void k_rowsum(const float* __restrict__ adj, float* __restrict__ dis){
  int i = blockIdx.x;
  const float4* row = reinterpret_cast<const float4*>(adj + (size_t)i * N);
  float s = 0.f;
  #pragma unroll
  for (int l = 0; l < 4; ++l){
    float4 v = row[threadIdx.x + l * 256];
    s += (v.x + v.y) + (v.z + v.w);
  }
  __shared__ float red[4];
  s = block_sum256(s, red);
  if (threadIdx.x == 0) dis[i] = 1.0f / sqrtf(s + EPSV);
}

// u = h @ W (split to bf16 hi/lo); p = h @ a_src ; q = h @ a_dst
__global__ void k_uhat2(const float* __restrict__ h, const float* __restrict__ W,
                        const float* __restrict__ aa,
                        ushort* __restrict__ u_hi, ushort* __restrict__ u_lo,
                        float* __restrict__ p, float* __restrict__ q){
  int i = blockIdx.x, t = threadIdx.x;
  __shared__ float hs[D];
  __shared__ float red[4];
  float hv = h[(size_t)i * D + t];
  hs[t] = hv;
  __syncthreads();
  float acc = 0.f;
  #pragma unroll 8
  for (int k = 0; k < D; ++k) acc = fmaf(hs[k], W[k * D + t], acc);
  ushort hh = bf16_hi(acc);
  u_hi[(size_t)i * D + t] = hh;
  u_lo[(size_t)i * D + t] = bf16_hi(acc - bf16_tof(hh));
  float pv = hv * aa[t];
  float qv = hv * aa[D + t];
  pv = wave_sum(pv); qv = wave_sum(qv);
  if ((t & 63) == 0){ red[t >> 6] = pv; red[2 + (t >> 6)] = qv; }
  __syncthreads();
  if (t == 0){ p[i] = red[0] + red[1]; q[i] = red[2] + red[3]; }
}

// transpose u_hi/u_lo (4096x128) -> packed uT_pk[n][kb][0:8]=hi, [8:16]=lo
__global__ void k_transposeU2(const ushort* __restrict__ u_hi, const ushort* __restrict__ u_lo,
                              ushort* __restrict__ uT_pk){
  __shared__ ushort T[64][136];
  const int tid = threadIdx.x;
  const int j0 = blockIdx.x * 64;
  for (int pass = 0; pass < 2; ++pass){
    const ushort* s = pass ? u_lo : u_hi;
    __syncthreads();
    #pragma unroll
    for (int l = 0; l < 4; ++l){
      int r = l * 16 + (tid >> 4);
      int c = (tid & 15) * 8;
      *reinterpret_cast<uint4*>(&T[r][c]) =
          *reinterpret_cast<const uint4*>(s + (size_t)(j0 + r) * D + c);
    }
    __syncthreads();
    const int dd = tid >> 1, half = tid & 1;
    #pragma unroll
    for (int g = 0; g < 4; ++g){
      int jb = half * 32 + g * 8;
      uint w0 = (uint)T[jb+0][dd] | ((uint)T[jb+1][dd] << 16);
      uint w1 = (uint)T[jb+2][dd] | ((uint)T[jb+3][dd] << 16);
      uint w2 = (uint)T[jb+4][dd] | ((uint)T[jb+5][dd] << 16);
      uint w3 = (uint)T[jb+6][dd] | ((uint)T[jb+7][dd] << 16);
      uint4 w; w.x = w0; w.y = w1; w.z = w2; w.w = w3;
      size_t off = ((size_t)dd * (N/8) + ((j0 + jb) >> 3)) * 16 + pass * 8;
      *reinterpret_cast<uint4*>(uT_pk + off) = w;
    }
  }
}

// ---------------------------------------------------------------------------
// No-stats MFMA gemm: s_part[y][i][n] = sum_{j in slab y} exp(logit_ij)*u[j][n]
// and l_part[y][i] = sum_j exp(logit_ij). No max subtraction (range-safe).
// MODE 0: logit = dis_i*dis_j*adj_ij ; MODE 1: logit = b_ij ;
// MODE 2: logit = lrelu(p_i + q_j)  (pure compute, src unused).
// Block 256 thr / 4 waves; wave = 16 rows x 128 cols; grid (64, KS).
// ---------------------------------------------------------------------------
template<int MODE>
__global__ __launch_bounds__(256, 4)
void k_gemm4(const float* __restrict__ src, const float* __restrict__ dis,
             const float* __restrict__ p, const float* __restrict__ q,
             const ushort* __restrict__ uT_pk,
             float* __restrict__ s_part, float* __restrict__ l_part, int kRange)
{
  const int lane = threadIdx.x & 63;
  const int wave = threadIdx.x >> 6;
  const int row0 = blockIdx.x * 64 + wave * 16;
  const int cl   = lane & 15;
  const int kgrp = (lane >> 4) * 8;
  const int arow = row0 + cl;
  const int k0b  = blockIdx.y * kRange;

  const float dif = (MODE == 0) ? dis[arow] : 0.f;
  const float pi  = (MODE == 2) ? p[arow] : 0.f;
  const float* srow = (MODE == 2) ? q : src + (size_t)arow * N;

  f32x4 acc[8] = {};
  float lsum = 0.f;

  // preload first A chunk (and dis chunk for MODE 0)
  float av[8], dv[8];
  {
    int kk = k0b + kgrp;
    *reinterpret_cast<float4*>(av)     = *reinterpret_cast<const float4*>(srow + kk);
    *reinterpret_cast<float4*>(av + 4) = *reinterpret_cast<const float4*>(srow + kk + 4);
    if (MODE == 0){
      *reinterpret_cast<float4*>(dv)     = *reinterpret_cast<const float4*>(dis + kk);
      *reinterpret_cast<float4*>(dv + 4) = *reinterpret_cast<const float4*>(dis + kk + 4);
    }
  }

  for (int kt = 0; kt < kRange; kt += 32){
    const int kk = k0b + kt + kgrp;
    // prefetch next A
    float4 n0, n1, m0, m1;
    const bool more = (kt + 32 < kRange);
    if (more){
      n0 = *reinterpret_cast<const float4*>(srow + kk + 32);
      n1 = *reinterpret_cast<const float4*>(srow + kk + 36);
      if (MODE == 0){
        m0 = *reinterpret_cast<const float4*>(dis + kk + 32);
        m1 = *reinterpret_cast<const float4*>(dis + kk + 36);
      }
    }
    // exp of logits
    float ex[8];
    #pragma unroll
    for (int e = 0; e < 8; ++e){
      float x;
      if (MODE == 0)      x = av[e] * dif * dv[e];
      else if (MODE == 1) x = av[e];
      else                x = lrelu(pi + av[e]);
      ex[e] = __expf(x);
      lsum += ex[e];
    }
    // split to bf16 hi/lo
    bf16x8 ahi, alo;
    #pragma unroll
    for (int e = 0; e < 8; ++e){
      ushort hh = bf16_hi(ex[e]);
      ahi[e] = (short)hh;
      alo[e] = (short)bf16_hi(ex[e] - bf16_tof(hh));
    }
    // B fragments from packed uT (hi|lo adjacent 32B) + MFMA
    const size_t kb16 = (size_t)(kk >> 3) * 16;
    #pragma unroll
    for (int ct = 0; ct < 8; ++ct){
      const ushort* bp = uT_pk + (size_t)(ct * 16 + cl) * (N/8) * 16 + kb16;
      bf16x8 bh = *reinterpret_cast<const bf16x8*>(bp);
      bf16x8 bl = *reinterpret_cast<const bf16x8*>(bp + 8);
      acc[ct] = __builtin_amdgcn_mfma_f32_16x16x32_bf16(ahi, bh, acc[ct], 0, 0, 0);
      acc[ct] = __builtin_amdgcn_mfma_f32_16x16x32_bf16(ahi, bl, acc[ct], 0, 0, 0);
      acc[ct] = __builtin_amdgcn_mfma_f32_16x16x32_bf16(alo, bh, acc[ct], 0, 0, 0);
    }
    if (more){
      *reinterpret_cast<float4*>(av)     = n0;
      *reinterpret_cast<float4*>(av + 4) = n1;
      if (MODE == 0){
        *reinterpret_cast<float4*>(dv)     = m0;
        *reinterpret_cast<float4*>(dv + 4) = m1;
      }
    }
  }

  // row-sum of exp: lanes {cl, cl+16, cl+32, cl+48} hold partials of row row0+cl
  lsum += __shfl_xor(lsum, 16);
  lsum += __shfl_xor(lsum, 32);
  if (lane < 16) l_part[(size_t)blockIdx.y * N + row0 + lane] = lsum;

  // C/D layout: col = lane&15, row = (lane>>4)*4 + reg (verified R4)
  const int orow = row0 + (lane >> 4) * 4;
  float* sp = s_part + ((size_t)blockIdx.y * N + orow) * D + cl;
  #pragma unroll
  for (int ct = 0; ct < 8; ++ct)
    #pragma unroll
    for (int r = 0; r < 4; ++r)
      sp[(size_t)r * D + ct * 16] = acc[ct][r];
}

// reduce attn slabs -> s_attn (raw numerator) + l_a (denominator)
__global__ void k_reduce_attn(const float* __restrict__ s_part, const float* __restrict__ l_part,
                              float* __restrict__ s_attn, float* __restrict__ l_a, int ks){
  int row = blockIdx.x, t = threadIdx.x;
  float a = 0.f;
  for (int y = 0; y < ks; ++y) a += s_part[((size_t)y * N + row) * D + t];
  s_attn[(size_t)row * D + t] = a;
  if (t == 0){
    float la = 0.f;
    for (int y = 0; y < ks; ++y) la += l_part[(size_t)y * N + row];
    l_a[row] = la;
  }
}

// reduce slabs, normalize, (optionally blend attn), squash.
// FINAL: out = squash(0.6*s_b/l_b + 0.4*s_attn/l_a) ; else v = squash(s_b/l_b)
template<bool FINAL>
__global__ void k_reduce_squash3(const float* __restrict__ s_part, const float* __restrict__ l_part,
                                 const float* __restrict__ s_attn, const float* __restrict__ l_a,
                                 float* __restrict__ out,
                                 ushort* __restrict__ vh, ushort* __restrict__ vl, int ks){
  int row = blockIdx.x, t = threadIdx.x;
  float a = 0.f;
  for (int y = 0; y < ks; ++y) a += s_part[((size_t)y * N + row) * D + t];
  __shared__ float lbs;
  __shared__ float red[2];
  if (t == 0){
    float lb = 0.f;
    for (int y = 0; y < ks; ++y) lb += l_part[(size_t)y * N + row];
    lbs = lb;
  }
  __syncthreads();
  float val;
  if (FINAL)
    val = 0.6f * a / lbs + 0.4f * s_attn[(size_t)row * D + t] / l_a[row];
  else
    val = a / lbs;
  float ss = wave_sum(val * val);
  if ((t & 63) == 0) red[t >> 6] = ss;
  __syncthreads();
  float tot = red[0] + red[1];
  float n = sqrtf(tot);
  float f = n / ((1.0f + n) * (n + EPSV));
  float o = val * f;
  if (FINAL) out[(size_t)row * D + t] = o;
  else {
    ushort hh = bf16_hi(o);
    vh[(size_t)row * D + t] = hh;
    vl[(size_t)row * D + t] = bf16_hi(o - bf16_tof(hh));
  }
}

// ---------------------------------------------------------------------------
// b-update via MFMA (verified R4): FIRST: b = d_i d_j adj + v@u^T ; else b += v@u^T
// ---------------------------------------------------------------------------
template<bool FIRST>
__global__ __launch_bounds__(256, 4)
void k_bupd3(const ushort* __restrict__ v_hi, const ushort* __restrict__ v_lo,
             const ushort* __restrict__ u_hi, const ushort* __restrict__ u_lo,
             const float* __restrict__ adj, const float* __restrict__ dis,
             float* __restrict__ b)
{
  const int lane = threadIdx.x & 63;
  const int wave = threadIdx.x >> 6;
  const int row0 = (blockIdx.x >> 5) * 128 + wave * 32;
  const int col0 = (blockIdx.x & 31) * 128;
  const int cl   = lane & 15;
  const int kgrp = (lane >> 4) * 8;

  f32x4 acc[2][8] = {};

  #pragma unroll
  for (int ks = 0; ks < 4; ++ks){
    const int kk = ks * 32 + kgrp;
    bf16x8 a_h[2], a_l[2];
    #pragma unroll
    for (int rt = 0; rt < 2; ++rt){
      size_t off = (size_t)(row0 + rt * 16 + cl) * D + kk;
      a_h[rt] = *reinterpret_cast<const bf16x8*>(v_hi + off);
      a_l[rt] = *reinterpret_cast<const bf16x8*>(v_lo + off);
    }
    #pragma unroll
    for (int ct = 0; ct < 8; ++ct){
      size_t off = (size_t)(col0 + ct * 16 + cl) * D + kk;
      bf16x8 b_h = *reinterpret_cast<const bf16x8*>(u_hi + off);
      bf16x8 b_l = *reinterpret_cast<const bf16x8*>(u_lo + off);
      #pragma unroll
      for (int rt = 0; rt < 2; ++rt){
        acc[rt][ct] = __builtin_amdgcn_mfma_f32_16x16x32_bf16(a_h[rt], b_h, acc[rt][ct], 0, 0, 0);
        acc[rt][ct] = __builtin_amdgcn_mfma_f32_16x16x32_bf16(a_h[rt], b_l, acc[rt][ct], 0, 0, 0);
        acc[rt][ct] = __builtin_amdgcn_mfma_f32_16x16x32_bf16(a_l[rt], b_h, acc[rt][ct], 0, 0, 0);
      }
    }
  }

  float dcol[8];
  if (FIRST){
    #pragma unroll
    for (int ct = 0; ct < 8; ++ct) dcol[ct] = dis[col0 + ct * 16 + cl];
  }
  #pragma unroll
  for (int rt = 0; rt < 2; ++rt){
    const int orow = row0 + rt * 16 + (lane >> 4) * 4;
    #pragma unroll
    for (int r = 0; r < 4; ++r){
      const int gr = orow + r;
      const float drow = FIRST ? dis[gr] : 0.f;
      size_t base = (size_t)gr * N + col0 + cl;
      #pragma unroll
      for (int ct = 0; ct < 8; ++ct){
        size_t idx = base + ct * 16;
        if (FIRST) b[idx] = fmaf(adj[idx], drow * dcol[ct], acc[rt][ct][r]);
        else       b[idx] += acc[rt][ct][r];
      }
    }
  }
}

extern "C" void kernel_launch(void* const* d_in, const int* in_sizes, int n_in,
                              void* d_out, int out_size, void* d_ws, size_t ws_size,
                              hipStream_t stream) {
  const float* h   = (const float*)d_in[0];
  const float* adj = (const float*)d_in[1];
  const float* W   = (const float*)d_in[2];
  const float* aa  = (const float*)d_in[3];
  float* out = (float*)d_out;
  float* ws  = (float*)d_ws;

  float* dis    = ws;            // 4096
  float* p      = ws + 4096;
  float* q      = ws + 8192;
  float* l_a    = ws + 12288;
  float* l_part = ws + 16384;    // up to 16*4096
  ushort* u_hi  = (ushort*)(ws + 81920);
  ushort* u_lo  = u_hi  + (size_t)N * D;
  ushort* uT_pk = u_lo  + (size_t)N * D;      // N/8 * 128 * 16 = 1,048,576 ushorts
  ushort* v_hi  = uT_pk + (size_t)(N/8) * D * 16;
  ushort* v_lo  = v_hi  + (size_t)N * D;
  float* s_attn = (float*)(v_lo + (size_t)N * D);   // 524288 floats
  float* b      = s_attn + (size_t)N * D;           // 16,777,216 floats
  float* s_part = b + (size_t)N * N;                // KS * 524288 floats

  size_t base_floats = (size_t)(s_part - ws);
  int KS = 16;
  while (KS > 1 && (base_floats + (size_t)KS * N * D) * 4 > ws_size) KS >>= 1;
  int kRange = N / KS;
  dim3 gg(64, KS);

  k_rowsum<<<N, 256, 0, stream>>>(adj, dis);
  k_uhat2<<<N, 128, 0, stream>>>(h, W, aa, u_hi, u_lo, p, q);
  k_transposeU2<<<64, 256, 0, stream>>>(u_hi, u_lo, uT_pk);

  // attention term (iteration-invariant): s_attn = exp(lrelu(p_i+q_j)) @ u ; l_a
  k_gemm4<2><<<gg, 256, 0, stream>>>(nullptr, dis, p, q, uT_pk, s_part, l_part, kRange);
  k_reduce_attn<<<N, 128, 0, stream>>>(s_part, l_part, s_attn, l_a, KS);

  // it 0: v1 = squash(softmax(adj_norm) @ u)
  k_gemm4<0><<<gg, 256, 0, stream>>>(adj, dis, p, q, uT_pk, s_part, l_part, kRange);
  k_reduce_squash3<false><<<N, 128, 0, stream>>>(s_part, l_part, s_attn, l_a, out, v_hi, v_lo, KS);
  // b1 = adj_norm + v1 @ u^T
  k_bupd3<true><<<1024, 256, 0, stream>>>(v_hi, v_lo, u_hi, u_lo, adj, dis, b);

  // it 1: v2 = squash(softmax(b1) @ u)
  k_gemm4<1><<<gg, 256, 0, stream>>>(b, dis, p, q, uT_pk, s_part, l_part, kRange);
  k_reduce_squash3<false><<<N, 128, 0, stream>>>(s_part, l_part, s_attn, l_a, out, v_hi, v_lo, KS);
  // b2 = b1 + v2 @ u^T
  k_bupd3<false><<<1024, 256, 0, stream>>>(v_hi, v_lo, u_hi, u_lo, adj, dis, b);

  // it 2 + final blend with attention term
  k_gemm4<1><<<gg, 256, 0, stream>>>(b, dis, p, q, uT_pk, s_part, l_part, kRange);
  k_reduce_squash3<true><<<N, 128, 0, stream>>>(s_part, l_part, s_attn, l_a, out, v_hi, v_lo, KS);
}

// Round 7
// 483.006 us; speedup vs baseline: 1.1432x; 1.1432x over previous
//
#include <hip/hip_runtime.h>
#include <hip/hip_bf16.h>
#include <math.h>

#define N 4096
#define D 128
#define EPSV 1e-8f

typedef __attribute__((ext_vector_type(8))) short bf16x8;
typedef __attribute__((ext_vector_type(4))) float f32x4;

__device__ __forceinline__ float lrelu(float x){ return x > 0.f ? x : 0.2f*x; }

__device__ __forceinline__ ushort bf16_hi(float x){
  __hip_bfloat16 h = __float2bfloat16(x);
  return *reinterpret_cast<ushort*>(&h);
}
__device__ __forceinline__ float bf16_tof(ushort u){
  __hip_bfloat16 h = *reinterpret_cast<__hip_bfloat16*>(&u);
  return __bfloat162float(h);
}

__device__ __forceinline__ float wave_sum(float v){
  #pragma unroll
  for (int off = 32; off; off >>= 1) v += __shfl_down(v, off);
  return v;
}
__device__ __forceinline__ float block_sum256(float v, float* red){
  v = wave_sum(v);
  if ((threadIdx.x & 63) == 0) red[threadIdx.x >> 6] = v;
  __syncthreads();
  float r = (red[0] + red[1]) + (red[2] + red[3]);
  __syncthreads();
  return r;
}

// dis[i] = 1/sqrt(sum_j adj[i][j] + 1e-8)
__global__ void k_rowsum(const float* __restrict__ adj, float* __restrict__ dis){
  int i = blockIdx.x;
  const float4* row = reinterpret_cast<const float4*>(adj + (size_t)i * N);
  float s = 0.f;
  #pragma unroll
  for (int l = 0; l < 4; ++l){
    float4 v = row[threadIdx.x + l * 256];
    s += (v.x + v.y) + (v.z + v.w);
  }
  __shared__ float red[4];
  s = block_sum256(s, red);
  if (threadIdx.x == 0) dis[i] = 1.0f / sqrtf(s + EPSV);
}

// u = h @ W (split to bf16 hi/lo); p = h @ a_src ; q = h @ a_dst
__global__ void k_uhat2(const float* __restrict__ h, const float* __restrict__ W,
                        const float* __restrict__ aa,
                        ushort* __restrict__ u_hi, ushort* __restrict__ u_lo,
                        float* __restrict__ p, float* __restrict__ q){
  int i = blockIdx.x, t = threadIdx.x;
  __shared__ float hs[D];
  __shared__ float red[4];
  float hv = h[(size_t)i * D + t];
  hs[t] = hv;
  __syncthreads();
  float acc = 0.f;
  #pragma unroll 8
  for (int k = 0; k < D; ++k) acc = fmaf(hs[k], W[k * D + t], acc);
  ushort hh = bf16_hi(acc);
  u_hi[(size_t)i * D + t] = hh;
  u_lo[(size_t)i * D + t] = bf16_hi(acc - bf16_tof(hh));
  float pv = hv * aa[t];
  float qv = hv * aa[D + t];
  pv = wave_sum(pv); qv = wave_sum(qv);
  if ((t & 63) == 0){ red[t >> 6] = pv; red[2 + (t >> 6)] = qv; }
  __syncthreads();
  if (t == 0){ p[i] = red[0] + red[1]; q[i] = red[2] + red[3]; }
}

// transpose u_hi/u_lo (4096x128) -> packed uT_pk[n][kb][0:8]=hi, [8:16]=lo
__global__ void k_transposeU2(const ushort* __restrict__ u_hi, const ushort* __restrict__ u_lo,
                              ushort* __restrict__ uT_pk){
  __shared__ ushort T[64][136];
  const int tid = threadIdx.x;
  const int j0 = blockIdx.x * 64;
  for (int pass = 0; pass < 2; ++pass){
    const ushort* s = pass ? u_lo : u_hi;
    __syncthreads();
    #pragma unroll
    for (int l = 0; l < 4; ++l){
      int r = l * 16 + (tid >> 4);
      int c = (tid & 15) * 8;
      *reinterpret_cast<uint4*>(&T[r][c]) =
          *reinterpret_cast<const uint4*>(s + (size_t)(j0 + r) * D + c);
    }
    __syncthreads();
    const int dd = tid >> 1, half = tid & 1;
    #pragma unroll
    for (int g = 0; g < 4; ++g){
      int jb = half * 32 + g * 8;
      uint w0 = (uint)T[jb+0][dd] | ((uint)T[jb+1][dd] << 16);
      uint w1 = (uint)T[jb+2][dd] | ((uint)T[jb+3][dd] << 16);
      uint w2 = (uint)T[jb+4][dd] | ((uint)T[jb+5][dd] << 16);
      uint w3 = (uint)T[jb+6][dd] | ((uint)T[jb+7][dd] << 16);
      uint4 w; w.x = w0; w.y = w1; w.z = w2; w.w = w3;
      size_t off = ((size_t)dd * (N/8) + ((j0 + jb) >> 3)) * 16 + pass * 8;
      *reinterpret_cast<uint4*>(uT_pk + off) = w;
    }
  }
}

// ---------------------------------------------------------------------------
// LDS-staged MFMA gemm: s_part[y][i][n] = sum_{j in slab y} exp(logit_ij)*u[j][n]
// l_part[y][i] = sum_j exp(logit_ij).  No max subtraction (range-safe, R5-proven).
// MODE 0: logit = dis_i*dis_j*adj_ij ; MODE 1: logit = b_ij ;
// MODE 2: logit = lrelu(p_i + q_j)  (src unused, no A-stage).
// Block 256 thr / 4 waves; tile M=128 x N=128; BK=32; grid (32, KS).
// ---------------------------------------------------------------------------
template<int MODE>
__global__ __launch_bounds__(256)
void k_gemm5(const float* __restrict__ src, const float* __restrict__ dis,
             const float* __restrict__ p, const float* __restrict__ q,
             const ushort* __restrict__ uT_pk,
             float* __restrict__ s_part, float* __restrict__ l_part, int kRange)
{
  __shared__ float  As[128][36];   // raw fp32 logit-source tile (144B rows)
  __shared__ ushort Bs[128][72];   // [col][hi 32 | lo 32 | pad 8]

  const int tid  = threadIdx.x;
  const int lane = tid & 63;
  const int wave = tid >> 6;
  const int row0 = blockIdx.x * 128;
  const int cl   = lane & 15;
  const int kgrp = (lane >> 4) * 8;
  const int k0b  = blockIdx.y * kRange;

  float dif[2], pr[2];
  #pragma unroll
  for (int rt = 0; rt < 2; ++rt){
    int ar = row0 + wave * 32 + rt * 16 + cl;
    dif[rt] = (MODE == 0) ? dis[ar] : 0.f;
    pr[rt]  = (MODE == 2) ? p[ar] : 0.f;
  }

  f32x4 acc[2][8] = {};
  float lsum[2] = {0.f, 0.f};

  for (int kt = 0; kt < kRange; kt += 32){
    const int kb = k0b + kt;
    // -------- stage loads (dense, coalesced) --------
    float4 a_st[4];
    if (MODE != 2){
      #pragma unroll
      for (int i = 0; i < 4; ++i){
        int idx = i * 256 + tid;
        int r = idx >> 3, c = idx & 7;
        a_st[i] = *reinterpret_cast<const float4*>(src + (size_t)(row0 + r) * N + kb + c * 4);
      }
    }
    uint4 b_st[4];
    const int kb8 = kb >> 3;
    #pragma unroll
    for (int i = 0; i < 4; ++i){
      int idx = i * 256 + tid;
      int n = idx >> 3, u = idx & 7;
      b_st[i] = *reinterpret_cast<const uint4*>(
          uT_pk + (size_t)n * (N/8) * 16 + (size_t)(kb8 + (u & 3)) * 16 + (u >> 2) * 8);
    }
    __syncthreads();
    if (MODE != 2){
      #pragma unroll
      for (int i = 0; i < 4; ++i){
        int idx = i * 256 + tid;
        int r = idx >> 3, c = idx & 7;
        *reinterpret_cast<float4*>(&As[r][c * 4]) = a_st[i];
      }
    }
    #pragma unroll
    for (int i = 0; i < 4; ++i){
      int idx = i * 256 + tid;
      int n = idx >> 3, u = idx & 7;
      *reinterpret_cast<uint4*>(&Bs[n][(u >> 2) * 32 + (u & 3) * 8]) = b_st[i];
    }
    __syncthreads();

    // -------- per-k-step scalars --------
    float aux[8];
    if (MODE == 0){
      *reinterpret_cast<float4*>(aux)     = *reinterpret_cast<const float4*>(dis + kb + kgrp);
      *reinterpret_cast<float4*>(aux + 4) = *reinterpret_cast<const float4*>(dis + kb + kgrp + 4);
    } else if (MODE == 2){
      *reinterpret_cast<float4*>(aux)     = *reinterpret_cast<const float4*>(q + kb + kgrp);
      *reinterpret_cast<float4*>(aux + 4) = *reinterpret_cast<const float4*>(q + kb + kgrp + 4);
    }

    // -------- A fragments: exp + split --------
    bf16x8 ahi[2], alo[2];
    #pragma unroll
    for (int rt = 0; rt < 2; ++rt){
      float ex[8];
      if (MODE == 2){
        #pragma unroll
        for (int e = 0; e < 8; ++e) ex[e] = __expf(lrelu(pr[rt] + aux[e]));
      } else {
        const int rl = wave * 32 + rt * 16 + cl;
        float av[8];
        *reinterpret_cast<float4*>(av)     = *reinterpret_cast<const float4*>(&As[rl][kgrp]);
        *reinterpret_cast<float4*>(av + 4) = *reinterpret_cast<const float4*>(&As[rl][kgrp + 4]);
        if (MODE == 0){
          #pragma unroll
          for (int e = 0; e < 8; ++e) ex[e] = __expf(av[e] * dif[rt] * aux[e]);
        } else {
          #pragma unroll
          for (int e = 0; e < 8; ++e) ex[e] = __expf(av[e]);
        }
      }
      #pragma unroll
      for (int e = 0; e < 8; ++e){
        lsum[rt] += ex[e];
        ushort hh = bf16_hi(ex[e]);
        ahi[rt][e] = (short)hh;
        alo[rt][e] = (short)bf16_hi(ex[e] - bf16_tof(hh));
      }
    }

    // -------- MFMA --------
    #pragma unroll
    for (int ct = 0; ct < 8; ++ct){
      const int col = ct * 16 + cl;
      bf16x8 bh = *reinterpret_cast<const bf16x8*>(&Bs[col][kgrp]);
      bf16x8 bl = *reinterpret_cast<const bf16x8*>(&Bs[col][32 + kgrp]);
      #pragma unroll
      for (int rt = 0; rt < 2; ++rt){
        acc[rt][ct] = __builtin_amdgcn_mfma_f32_16x16x32_bf16(ahi[rt], bh, acc[rt][ct], 0, 0, 0);
        acc[rt][ct] = __builtin_amdgcn_mfma_f32_16x16x32_bf16(ahi[rt], bl, acc[rt][ct], 0, 0, 0);
        acc[rt][ct] = __builtin_amdgcn_mfma_f32_16x16x32_bf16(alo[rt], bh, acc[rt][ct], 0, 0, 0);
      }
    }
  }

  // row-sums of exp
  #pragma unroll
  for (int rt = 0; rt < 2; ++rt){
    float l = lsum[rt];
    l += __shfl_xor(l, 16);
    l += __shfl_xor(l, 32);
    if (lane < 16)
      l_part[(size_t)blockIdx.y * N + row0 + wave * 32 + rt * 16 + lane] = l;
  }
  // C/D layout: col = lane&15, row = (lane>>4)*4 + reg (verified R4/R5)
  #pragma unroll
  for (int rt = 0; rt < 2; ++rt){
    const int orow = row0 + wave * 32 + rt * 16 + (lane >> 4) * 4;
    float* sp = s_part + ((size_t)blockIdx.y * N + orow) * D + cl;
    #pragma unroll
    for (int ct = 0; ct < 8; ++ct)
      #pragma unroll
      for (int r = 0; r < 4; ++r)
        sp[(size_t)r * D + ct * 16] = acc[rt][ct][r];
  }
}

// reduce attn slabs -> s_attn (raw numerator) + l_a (denominator)
__global__ void k_reduce_attn(const float* __restrict__ s_part, const float* __restrict__ l_part,
                              float* __restrict__ s_attn, float* __restrict__ l_a, int ks){
  int row = blockIdx.x, t = threadIdx.x;
  float a = 0.f;
  for (int y = 0; y < ks; ++y) a += s_part[((size_t)y * N + row) * D + t];
  s_attn[(size_t)row * D + t] = a;
  if (t == 0){
    float la = 0.f;
    for (int y = 0; y < ks; ++y) la += l_part[(size_t)y * N + row];
    l_a[row] = la;
  }
}

// reduce slabs, normalize, (optionally blend attn), squash.
template<bool FINAL>
__global__ void k_reduce_squash3(const float* __restrict__ s_part, const float* __restrict__ l_part,
                                 const float* __restrict__ s_attn, const float* __restrict__ l_a,
                                 float* __restrict__ out,
                                 ushort* __restrict__ vh, ushort* __restrict__ vl, int ks){
  int row = blockIdx.x, t = threadIdx.x;
  float a = 0.f;
  for (int y = 0; y < ks; ++y) a += s_part[((size_t)y * N + row) * D + t];
  __shared__ float lbs;
  __shared__ float red[2];
  if (t == 0){
    float lb = 0.f;
    for (int y = 0; y < ks; ++y) lb += l_part[(size_t)y * N + row];
    lbs = lb;
  }
  __syncthreads();
  float val;
  if (FINAL)
    val = 0.6f * a / lbs + 0.4f * s_attn[(size_t)row * D + t] / l_a[row];
  else
    val = a / lbs;
  float ss = wave_sum(val * val);
  if ((t & 63) == 0) red[t >> 6] = ss;
  __syncthreads();
  float tot = red[0] + red[1];
  float n = sqrtf(tot);
  float f = n / ((1.0f + n) * (n + EPSV));
  float o = val * f;
  if (FINAL) out[(size_t)row * D + t] = o;
  else {
    ushort hh = bf16_hi(o);
    vh[(size_t)row * D + t] = hh;
    vl[(size_t)row * D + t] = bf16_hi(o - bf16_tof(hh));
  }
}

// ---------------------------------------------------------------------------
// b-update via MFMA, LDS-staged operands + dense RMW epilogue via LDS transpose.
// FIRST: b = d_i d_j adj + v@u^T ; else b += v@u^T
// Block 256 thr / 4 waves; tile 128x128; K=128 in 4 slabs of 32. grid = 1024.
// FIX (R7): single explicit LDS pool — vs@0 (18432B), us@18432 (18432B),
// tr@0 (33792B) overlaps both but stays inside the 36864B allocation.
// R6's tr spilled past vs's 18432B into compiler-ordered memory (UB -> corrupt b).
// ---------------------------------------------------------------------------
template<bool FIRST>
__global__ __launch_bounds__(256)
void k_bupd5(const ushort* __restrict__ v_hi, const ushort* __restrict__ v_lo,
             const ushort* __restrict__ u_hi, const ushort* __restrict__ u_lo,
             const float* __restrict__ adj, const float* __restrict__ dis,
             float* __restrict__ b)
{
  __shared__ __align__(16) char smem[36864];
  ushort (*vs)[72] = reinterpret_cast<ushort(*)[72]>(smem);            // [128][72]
  ushort (*us)[72] = reinterpret_cast<ushort(*)[72]>(smem + 18432);    // [128][72]
  float*  tr       = reinterpret_cast<float*>(smem);                   // [64][132]

  const int tid  = threadIdx.x;
  const int lane = tid & 63;
  const int wave = tid >> 6;
  const int row0 = (blockIdx.x >> 5) * 128;
  const int col0 = (blockIdx.x & 31) * 128;
  const int cl   = lane & 15;
  const int kgrp = (lane >> 4) * 8;

  f32x4 acc[2][8] = {};

  #pragma unroll
  for (int ks = 0; ks < 4; ++ks){
    const int kk = ks * 32;
    uint4 v_st[4], u_st[4];
    #pragma unroll
    for (int i = 0; i < 4; ++i){
      int idx = i * 256 + tid;
      int r = idx >> 3, uu = idx & 7;
      const ushort* vsrc = (uu < 4) ? v_hi : v_lo;
      v_st[i] = *reinterpret_cast<const uint4*>(vsrc + (size_t)(row0 + r) * D + kk + (uu & 3) * 8);
      const ushort* usrc = (uu < 4) ? u_hi : u_lo;
      u_st[i] = *reinterpret_cast<const uint4*>(usrc + (size_t)(col0 + r) * D + kk + (uu & 3) * 8);
    }
    __syncthreads();
    #pragma unroll
    for (int i = 0; i < 4; ++i){
      int idx = i * 256 + tid;
      int r = idx >> 3, uu = idx & 7;
      *reinterpret_cast<uint4*>(&vs[r][(uu >> 2) * 32 + (uu & 3) * 8]) = v_st[i];
      *reinterpret_cast<uint4*>(&us[r][(uu >> 2) * 32 + (uu & 3) * 8]) = u_st[i];
    }
    __syncthreads();

    bf16x8 a_h[2], a_l[2];
    #pragma unroll
    for (int rt = 0; rt < 2; ++rt){
      const int rl = wave * 32 + rt * 16 + cl;
      a_h[rt] = *reinterpret_cast<const bf16x8*>(&vs[rl][kgrp]);
      a_l[rt] = *reinterpret_cast<const bf16x8*>(&vs[rl][32 + kgrp]);
    }
    #pragma unroll
    for (int ct = 0; ct < 8; ++ct){
      const int col = ct * 16 + cl;
      bf16x8 b_h = *reinterpret_cast<const bf16x8*>(&us[col][kgrp]);
      bf16x8 b_l = *reinterpret_cast<const bf16x8*>(&us[col][32 + kgrp]);
      #pragma unroll
      for (int rt = 0; rt < 2; ++rt){
        acc[rt][ct] = __builtin_amdgcn_mfma_f32_16x16x32_bf16(a_h[rt], b_h, acc[rt][ct], 0, 0, 0);
        acc[rt][ct] = __builtin_amdgcn_mfma_f32_16x16x32_bf16(a_h[rt], b_l, acc[rt][ct], 0, 0, 0);
        acc[rt][ct] = __builtin_amdgcn_mfma_f32_16x16x32_bf16(a_l[rt], b_h, acc[rt][ct], 0, 0, 0);
      }
    }
    __syncthreads();   // protect LDS before next slab / epilogue reuse
  }

  // dense epilogue: two passes (rt), acc -> LDS [64][132] -> full-line RMW
  #pragma unroll
  for (int rt = 0; rt < 2; ++rt){
    #pragma unroll
    for (int ct = 0; ct < 8; ++ct)
      #pragma unroll
      for (int r = 0; r < 4; ++r)
        tr[(wave * 16 + (lane >> 4) * 4 + r) * 132 + ct * 16 + cl] = acc[rt][ct][r];
    __syncthreads();
    #pragma unroll
    for (int i = 0; i < 8; ++i){
      int idx = i * 256 + tid;
      int rl = idx >> 5, c4 = (idx & 31) * 4;
      int grow = row0 + (rl >> 4) * 32 + rt * 16 + (rl & 15);
      float4 v = *reinterpret_cast<const float4*>(&tr[rl * 132 + c4]);
      size_t gidx = (size_t)grow * N + col0 + c4;
      float4 o;
      if (FIRST){
        float4 ad = *reinterpret_cast<const float4*>(adj + gidx);
        float dr = dis[grow];
        float4 dc = *reinterpret_cast<const float4*>(dis + col0 + c4);
        o.x = fmaf(ad.x, dr * dc.x, v.x);
        o.y = fmaf(ad.y, dr * dc.y, v.y);
        o.z = fmaf(ad.z, dr * dc.z, v.z);
        o.w = fmaf(ad.w, dr * dc.w, v.w);
      } else {
        float4 bo = *reinterpret_cast<const float4*>(b + gidx);
        o.x = bo.x + v.x; o.y = bo.y + v.y; o.z = bo.z + v.z; o.w = bo.w + v.w;
      }
      *reinterpret_cast<float4*>(b + gidx) = o;
    }
    __syncthreads();
  }
}

extern "C" void kernel_launch(void* const* d_in, const int* in_sizes, int n_in,
                              void* d_out, int out_size, void* d_ws, size_t ws_size,
                              hipStream_t stream) {
  const float* h   = (const float*)d_in[0];
  const float* adj = (const float*)d_in[1];
  const float* W   = (const float*)d_in[2];
  const float* aa  = (const float*)d_in[3];
  float* out = (float*)d_out;
  float* ws  = (float*)d_ws;

  float* dis    = ws;            // 4096
  float* p      = ws + 4096;
  float* q      = ws + 8192;
  float* l_a    = ws + 12288;
  float* l_part = ws + 16384;    // up to 16*4096
  ushort* u_hi  = (ushort*)(ws + 81920);
  ushort* u_lo  = u_hi  + (size_t)N * D;
  ushort* uT_pk = u_lo  + (size_t)N * D;      // N/8 * 128 * 16 = 1,048,576 ushorts
  ushort* v_hi  = uT_pk + (size_t)(N/8) * D * 16;
  ushort* v_lo  = v_hi  + (size_t)N * D;
  float* s_attn = (float*)(v_lo + (size_t)N * D);   // 524288 floats
  float* b      = s_attn + (size_t)N * D;           // 16,777,216 floats
  float* s_part = b + (size_t)N * N;                // KS * 524288 floats

  size_t base_floats = (size_t)(s_part - ws);
  int KS = 16;
  while (KS > 1 && (base_floats + (size_t)KS * N * D) * 4 > ws_size) KS >>= 1;
  int kRange = N / KS;
  dim3 gg(32, KS);

  k_rowsum<<<N, 256, 0, stream>>>(adj, dis);
  k_uhat2<<<N, 128, 0, stream>>>(h, W, aa, u_hi, u_lo, p, q);
  k_transposeU2<<<64, 256, 0, stream>>>(u_hi, u_lo, uT_pk);

  // attention term (iteration-invariant): s_attn = exp(lrelu(p_i+q_j)) @ u ; l_a
  k_gemm5<2><<<gg, 256, 0, stream>>>(nullptr, dis, p, q, uT_pk, s_part, l_part, kRange);
  k_reduce_attn<<<N, 128, 0, stream>>>(s_part, l_part, s_attn, l_a, KS);

  // it 0: v1 = squash(softmax(adj_norm) @ u)
  k_gemm5<0><<<gg, 256, 0, stream>>>(adj, dis, p, q, uT_pk, s_part, l_part, kRange);
  k_reduce_squash3<false><<<N, 128, 0, stream>>>(s_part, l_part, s_attn, l_a, out, v_hi, v_lo, KS);
  // b1 = adj_norm + v1 @ u^T
  k_bupd5<true><<<1024, 256, 0, stream>>>(v_hi, v_lo, u_hi, u_lo, adj, dis, b);

  // it 1: v2 = squash(softmax(b1) @ u)
  k_gemm5<1><<<gg, 256, 0, stream>>>(b, dis, p, q, uT_pk, s_part, l_part, kRange);
  k_reduce_squash3<false><<<N, 128, 0, stream>>>(s_part, l_part, s_attn, l_a, out, v_hi, v_lo, KS);
  // b2 = b1 + v2 @ u^T
  k_bupd5<false><<<1024, 256, 0, stream>>>(v_hi, v_lo, u_hi, u_lo, adj, dis, b);

  // it 2 + final blend with attention term
  k_gemm5<1><<<gg, 256, 0, stream>>>(b, dis, p, q, uT_pk, s_part, l_part, kRange);
  k_reduce_squash3<true><<<N, 128, 0, stream>>>(s_part, l_part, s_attn, l_a, out, v_hi, v_lo, KS);
}